// Round 6
// baseline (272.218 us; speedup 1.0000x reference)
//
#include <hip/hip_runtime.h>
#include <hip/hip_bf16.h>

// Problem constants (match reference setup_inputs)
#define BATCH 4096
#define P     64
#define L     1024            // floats per (b,p) block = 4 KiB
#define LT    256             // samples per block
#define NPAIRS (BATCH * P)    // 262144
#define WPB   2               // waves per block (128 threads)
#define NBLK  1280            // 5 blocks/CU x 256 CU, exactly resident
#define NWAVES (NBLK * WPB)   // 2560 waves; 102.4 pairs/wave (102 or 103)
#define DEPTH 4               // quad-buffer: 3 tiles in flight per wave

// 4-deep per-wave pipeline, zero block coupling:
//   iter i: stage tile i+3 (4x global_load_lds dwordx4 -> LDS DMA),
//           s_waitcnt vmcnt(12)  [drains tile i's loads + old stores],
//           gather 4 floats/lane from buf i%4, nontemporal float4 store.
// In flight per wave: 3 tiles = 12 KiB; 10 waves/CU -> 120 KiB/CU, sized
// against loaded (queued) HBM latency rather than nominal latency.
//
// vmcnt ledger (FIFO), steady state right after staging i+3:
//   [loads(i) (maybe done), store(i-1), loads(i+1) x4, (i+2) x4, (i+3) x4]
//   12 newest = loads(i+1..i+3) -> vmcnt(12) guarantees tile i + store done.
// Tail: i=n-3 -> vmcnt(8), i=n-2 -> vmcnt(4), i=n-1 -> vmcnt(0).

typedef const __attribute__((address_space(1))) void* gptr_t;
typedef __attribute__((address_space(3))) void* lptr_t;
typedef float nfloat4 __attribute__((ext_vector_type(4)));

__device__ __forceinline__ void stage_tile(const float* gsrc_lane,
                                           float* lds_base) {
    // 4 chunks x (64 lanes x 16 B) = 4 KiB; LDS dest = uniform base + lane*16
    __builtin_amdgcn_global_load_lds((gptr_t)(gsrc_lane),       (lptr_t)(lds_base),       16, 0, 0);
    __builtin_amdgcn_global_load_lds((gptr_t)(gsrc_lane + 256), (lptr_t)(lds_base + 256), 16, 0, 0);
    __builtin_amdgcn_global_load_lds((gptr_t)(gsrc_lane + 512), (lptr_t)(lds_base + 512), 16, 0, 0);
    __builtin_amdgcn_global_load_lds((gptr_t)(gsrc_lane + 768), (lptr_t)(lds_base + 768), 16, 0, 0);
}

__global__ __launch_bounds__(128)
void HardSamplingLayer_5360119186055_kernel(const float* __restrict__ x,
                                            const int* __restrict__ w,
                                            float* __restrict__ out) {
    __shared__ float tile[WPB][DEPTH][L];   // 32 KiB/block

    const int t  = threadIdx.x & 63;        // lane
    const int wv = threadIdx.x >> 6;        // wave id within block

    // per-lane gather indices (output columns 4t..4t+3), loaded once
    const int4 wi = ((const int4*)w)[t];

    const int wid = blockIdx.x * WPB + wv;              // 0..2559
    const int beg = (int)(((long long)wid * NPAIRS) / NWAVES);
    const int end = (int)(((long long)(wid + 1) * NPAIRS) / NWAVES);
    const int n   = end - beg;                          // 102 or 103

    const float* gsrc = x + (size_t)beg * L + t * 4;    // lane's 16B slot
    float*       gdst = out + (size_t)beg * LT;

    // prologue: stage tiles 0..2 (n >= 102 always)
    stage_tile(gsrc,           &tile[wv][0][0]);
    stage_tile(gsrc + L,       &tile[wv][1][0]);
    stage_tile(gsrc + 2 * L,   &tile[wv][2][0]);

    for (int i = 0; i < n; ++i) {
        if (i + 3 < n) {
            stage_tile(gsrc + (size_t)(i + 3) * L, &tile[wv][(i + 3) & 3][0]);
            asm volatile("s_waitcnt vmcnt(12)" ::: "memory");
        } else if (i + 2 < n) {
            asm volatile("s_waitcnt vmcnt(8)" ::: "memory");
        } else if (i + 1 < n) {
            asm volatile("s_waitcnt vmcnt(4)" ::: "memory");
        } else {
            asm volatile("s_waitcnt vmcnt(0)" ::: "memory");
        }

        const float* mytile = &tile[wv][i & 3][0];
        nfloat4 o;
        o.x = mytile[wi.x];
        o.y = mytile[wi.y];
        o.z = mytile[wi.z];
        o.w = mytile[wi.w];

        // coalesced 16B/lane nontemporal store (wave covers full 1 KiB row)
        __builtin_nontemporal_store(o, (nfloat4*)(gdst + (size_t)i * LT) + t);
    }
}

extern "C" void kernel_launch(void* const* d_in, const int* in_sizes, int n_in,
                              void* d_out, int out_size, void* d_ws, size_t ws_size,
                              hipStream_t stream) {
    const float* x = (const float*)d_in[0];
    const int*   w = (const int*)d_in[1];   // integer input -> const int*
    float*     out = (float*)d_out;

    dim3 grid(NBLK), block(128);
    hipLaunchKernelGGL(HardSamplingLayer_5360119186055_kernel,
                       grid, block, 0, stream, x, w, out);
}

// Round 7
// 243.204 us; speedup vs baseline: 1.1193x; 1.1193x over previous
//
#include <hip/hip_runtime.h>
#include <hip/hip_bf16.h>

// Problem constants (match reference setup_inputs)
#define BATCH 4096
#define P     64
#define L     1024            // floats per (b,p) block = 4 KiB
#define LT    256             // samples per block
#define NPAIRS (BATCH * P)    // 262144
#define WPB   4               // waves per block (256 threads)
#define NBLK  4096
#define PPW   (NPAIRS / (NBLK * WPB))   // 16 pairs per wave, contiguous

// Best-so-far structure (R5, 258us) + NT cache policy on the read stream:
// each 64-lane wave owns a private double-buffered 2x4 KiB LDS tile and
// processes 16 CONTIGUOUS (b,p) pairs. Staging uses global_load_lds with
// aux=2 (CPol NT: x is streamed once, zero reuse -> don't allocate L2/L3)
// and hand-counted s_waitcnt vmcnt(4). Zero __syncthreads.
//
// vmcnt ledger (FIFO): at iter i's wait point, outstanding =
//   [store(i-1)] [4 loads -> buf^1 (tile i+1)]
// vmcnt(4) drains store(i-1) and everything older, incl. tile i's loads.
// Last iter: vmcnt(0).

typedef const __attribute__((address_space(1))) void* gptr_t;
typedef __attribute__((address_space(3))) void* lptr_t;
typedef float nfloat4 __attribute__((ext_vector_type(4)));

#define CPOL_NT 2   // gfx940+/gfx950 CPol: SC0=1, NT=2, SC1=16

__device__ __forceinline__ void stage_tile(const float* gsrc_lane,
                                           float* lds_base) {
    // 4 chunks x (64 lanes x 16 B) = 4 KiB; LDS dest = uniform base + lane*16
    __builtin_amdgcn_global_load_lds((gptr_t)(gsrc_lane),        (lptr_t)(lds_base),        16, 0, CPOL_NT);
    __builtin_amdgcn_global_load_lds((gptr_t)(gsrc_lane + 256),  (lptr_t)(lds_base + 256),  16, 0, CPOL_NT);
    __builtin_amdgcn_global_load_lds((gptr_t)(gsrc_lane + 512),  (lptr_t)(lds_base + 512),  16, 0, CPOL_NT);
    __builtin_amdgcn_global_load_lds((gptr_t)(gsrc_lane + 768),  (lptr_t)(lds_base + 768),  16, 0, CPOL_NT);
}

__global__ __launch_bounds__(256)
void HardSamplingLayer_5360119186055_kernel(const float* __restrict__ x,
                                            const int* __restrict__ w,
                                            float* __restrict__ out) {
    __shared__ float tile[WPB][2][L];     // 32 KiB: per-wave double buffer

    const int t  = threadIdx.x & 63;      // lane
    const int wv = threadIdx.x >> 6;      // wave id within block

    // per-lane gather indices (columns 4t..4t+3), constant across pairs
    const int4 wi = ((const int4*)w)[t];

    const int    wid   = blockIdx.x * WPB + wv;       // 0..16383
    const size_t pair0 = (size_t)wid * PPW;           // 16 contiguous pairs
    const float* gsrc  = x + pair0 * L + t * 4;       // lane's 16B slot
    float*       gdst  = out + pair0 * LT;

    // prologue: stage pair0 -> buf0
    stage_tile(gsrc, &tile[wv][0][0]);

#pragma unroll
    for (int i = 0; i < PPW; ++i) {
        const int buf = i & 1;
        if (i + 1 < PPW) {
            stage_tile(gsrc + (size_t)(i + 1) * L, &tile[wv][buf ^ 1][0]);
            asm volatile("s_waitcnt vmcnt(4)" ::: "memory");  // cur tile ready
        } else {
            asm volatile("s_waitcnt vmcnt(0)" ::: "memory");  // drain all
        }

        const float* mytile = &tile[wv][buf][0];
        nfloat4 o;
        o.x = mytile[wi.x];
        o.y = mytile[wi.y];
        o.z = mytile[wi.z];
        o.w = mytile[wi.w];

        // coalesced 16B/lane nontemporal store (full 1 KiB row per wave)
        __builtin_nontemporal_store(o, (nfloat4*)(gdst + (size_t)i * LT) + t);
    }
}

extern "C" void kernel_launch(void* const* d_in, const int* in_sizes, int n_in,
                              void* d_out, int out_size, void* d_ws, size_t ws_size,
                              hipStream_t stream) {
    const float* x = (const float*)d_in[0];
    const int*   w = (const int*)d_in[1];   // integer input -> const int*
    float*     out = (float*)d_out;

    // 4096 blocks x 4 waves x 16 pairs = 262144, exact
    dim3 grid(NBLK), block(256);
    hipLaunchKernelGGL(HardSamplingLayer_5360119186055_kernel,
                       grid, block, 0, stream, x, w, out);
}

// Round 8
// 240.058 us; speedup vs baseline: 1.1340x; 1.0131x over previous
//
#include <hip/hip_runtime.h>
#include <hip/hip_bf16.h>

// Problem constants (match reference setup_inputs)
#define BATCH 4096
#define P     64
#define L     1024            // floats per (b,p) block = 4 KiB
#define LT    256             // samples per block
#define NPAIRS (BATCH * P)    // 262144
#define WPB   4               // waves per block (256 threads)
#define NBLK  4096
#define PPW   (NPAIRS / (NBLK * WPB))   // 16 pairs per wave, contiguous

// R7 structure (243us) + store-decoupled waits:
// each 64-lane wave owns a private double-buffered 2x4 KiB LDS tile and
// processes 16 CONTIGUOUS (b,p) pairs. Staging uses global_load_lds with
// aux=2 (CPol NT: x streamed once, don't allocate L2/L3), output via NT
// float4 stores. Waits never block on store completion in steady state:
//   i=0:      [L0 x4, L1 x4]                     -> vmcnt(4)
//   1<=i<=14: [S(i-2), L(i) x4, S(i-1), L(i+1) x4] -> vmcnt(5)
//             (drains S(i-2)+L(i); S(i-1) rides one more iter)
//   i=15:     [S13, L15 x4, S14]                 -> vmcnt(1)
// LDS hazard: stage(i+1) writes the buffer last read by tile i-1, whose
// ds_reads completed (register dep through o) before S(i-1) issued, and
// stage(i+1) is issued after S(i-1). No race. Zero __syncthreads.

typedef const __attribute__((address_space(1))) void* gptr_t;
typedef __attribute__((address_space(3))) void* lptr_t;
typedef float nfloat4 __attribute__((ext_vector_type(4)));

#define CPOL_NT 2   // gfx940+/gfx950 CPol: SC0=1, NT=2, SC1=16

__device__ __forceinline__ void stage_tile(const float* gsrc_lane,
                                           float* lds_base) {
    // 4 chunks x (64 lanes x 16 B) = 4 KiB; LDS dest = uniform base + lane*16
    __builtin_amdgcn_global_load_lds((gptr_t)(gsrc_lane),        (lptr_t)(lds_base),        16, 0, CPOL_NT);
    __builtin_amdgcn_global_load_lds((gptr_t)(gsrc_lane + 256),  (lptr_t)(lds_base + 256),  16, 0, CPOL_NT);
    __builtin_amdgcn_global_load_lds((gptr_t)(gsrc_lane + 512),  (lptr_t)(lds_base + 512),  16, 0, CPOL_NT);
    __builtin_amdgcn_global_load_lds((gptr_t)(gsrc_lane + 768),  (lptr_t)(lds_base + 768),  16, 0, CPOL_NT);
}

__global__ __launch_bounds__(256)
void HardSamplingLayer_5360119186055_kernel(const float* __restrict__ x,
                                            const int* __restrict__ w,
                                            float* __restrict__ out) {
    __shared__ float tile[WPB][2][L];     // 32 KiB: per-wave double buffer

    const int t  = threadIdx.x & 63;      // lane
    const int wv = threadIdx.x >> 6;      // wave id within block

    // per-lane gather indices (columns 4t..4t+3), constant across pairs
    const int4 wi = ((const int4*)w)[t];

    const int    wid   = blockIdx.x * WPB + wv;       // 0..16383
    const size_t pair0 = (size_t)wid * PPW;           // 16 contiguous pairs
    const float* gsrc  = x + pair0 * L + t * 4;       // lane's 16B slot
    float*       gdst  = out + pair0 * LT;

    // prologue: stage pair0 -> buf0
    stage_tile(gsrc, &tile[wv][0][0]);

#pragma unroll
    for (int i = 0; i < PPW; ++i) {
        const int buf = i & 1;
        if (i + 1 < PPW) {
            stage_tile(gsrc + (size_t)(i + 1) * L, &tile[wv][buf ^ 1][0]);
            if (i == 0) {
                asm volatile("s_waitcnt vmcnt(4)" ::: "memory");  // no stores yet
            } else {
                asm volatile("s_waitcnt vmcnt(5)" ::: "memory");  // skip S(i-1)
            }
        } else {
            asm volatile("s_waitcnt vmcnt(1)" ::: "memory");      // leave S(14)
        }

        const float* mytile = &tile[wv][buf][0];
        nfloat4 o;
        o.x = mytile[wi.x];
        o.y = mytile[wi.y];
        o.z = mytile[wi.z];
        o.w = mytile[wi.w];

        // coalesced 16B/lane nontemporal store (full 1 KiB row per wave)
        __builtin_nontemporal_store(o, (nfloat4*)(gdst + (size_t)i * LT) + t);
    }
}

extern "C" void kernel_launch(void* const* d_in, const int* in_sizes, int n_in,
                              void* d_out, int out_size, void* d_ws, size_t ws_size,
                              hipStream_t stream) {
    const float* x = (const float*)d_in[0];
    const int*   w = (const int*)d_in[1];   // integer input -> const int*
    float*     out = (float*)d_out;

    // 4096 blocks x 4 waves x 16 pairs = 262144, exact
    dim3 grid(NBLK), block(256);
    hipLaunchKernelGGL(HardSamplingLayer_5360119186055_kernel,
                       grid, block, 0, stream, x, w, out);
}